// Round 6
// baseline (2385.294 us; speedup 1.0000x reference)
//
#include <hip/hip_runtime.h>
#include <stdint.h>

#define EPSV 1e-5f

constexpr int Nn = 25000;
constexpr int Ee = 400000;
constexpr int Gg = 128;
constexpr int NF = 92;
constexpr int EF = 41;
constexpr int Fd = 64;
constexpr int K3 = 192;
constexpr int NC = 3;

__device__ __forceinline__ float d_sigmoid(float x) { return 1.f / (1.f + __expf(-x)); }
__device__ __forceinline__ float d_silu(float x)    { return x / (1.f + __expf(-x)); }
__device__ __forceinline__ float d_softplus(float x){ return fmaxf(x, 0.f) + __logf(1.f + __expf(-fabsf(x))); }

// ---------------- embedding GEMM: Y[M,64] = X[M,KIN] @ W[KIN,64] + b, with col stats ----------------
template<int KIN>
__global__ __launch_bounds__(256)
void embed_gemm(const float* __restrict__ X, const float* __restrict__ W,
                const float* __restrict__ bias, float* __restrict__ Y,
                float* __restrict__ statp, int M)
{
  constexpr int KC = 32;
  __shared__ float Xs[KC][68];   // transposed: Xs[k][row]
  __shared__ float Ws[KC][68];   // Ws[k][col]
  const int t = threadIdx.x;
  const int row0 = blockIdx.x * 64;
  const int tr = t & 15, tc = t >> 4;
  const int r0 = tr * 4, c0 = tc * 4;
  float acc[4][4] = {};
  constexpr int NKT = (KIN + KC - 1) / KC;
  const int lr = t >> 2;
  const int lk = (t & 3) * 8;
  const int wk = t >> 3;
  const int wc = (t & 7) * 8;
  for (int kt = 0; kt < NKT; ++kt) {
    const int k0 = kt * KC;
#pragma unroll
    for (int u = 0; u < 2; ++u) {
      const int kk = lk + u * 4;
      float v[4] = {0.f, 0.f, 0.f, 0.f};
      const int grow = row0 + lr;
      if (grow < M) {
        const float* xr = X + (size_t)grow * KIN + k0 + kk;
#pragma unroll
        for (int q = 0; q < 4; ++q)
          if (k0 + kk + q < KIN) v[q] = xr[q];
      }
      Xs[kk + 0][lr] = v[0]; Xs[kk + 1][lr] = v[1];
      Xs[kk + 2][lr] = v[2]; Xs[kk + 3][lr] = v[3];
    }
#pragma unroll
    for (int u = 0; u < 2; ++u) {
      const int cc = wc + u * 4;
      float4 wv = make_float4(0.f, 0.f, 0.f, 0.f);
      if (k0 + wk < KIN) wv = *(const float4*)(W + (size_t)(k0 + wk) * Fd + cc);
      *(float4*)&Ws[wk][cc] = wv;
    }
    __syncthreads();
#pragma unroll
    for (int k = 0; k < KC; ++k) {
      const float4 xv = *(const float4*)&Xs[k][r0];
      const float4 wv = *(const float4*)&Ws[k][c0];
      const float xa[4] = {xv.x, xv.y, xv.z, xv.w};
      const float wa[4] = {wv.x, wv.y, wv.z, wv.w};
#pragma unroll
      for (int i = 0; i < 4; ++i)
#pragma unroll
        for (int j = 0; j < 4; ++j)
          acc[i][j] = fmaf(xa[i], wa[j], acc[i][j]);
    }
    __syncthreads();
  }
  float bv[4];
#pragma unroll
  for (int j = 0; j < 4; ++j) bv[j] = bias[c0 + j];
  float s1[4] = {}, s2[4] = {};
#pragma unroll
  for (int i = 0; i < 4; ++i) {
    const int grow = row0 + r0 + i;
    if (grow < M) {
      float4 yv;
      float* yp = (float*)&yv;
#pragma unroll
      for (int j = 0; j < 4; ++j) {
        const float y = acc[i][j] + bv[j];
        yp[j] = y; s1[j] += y; s2[j] += y * y;
      }
      *(float4*)(Y + (size_t)grow * Fd + c0) = yv;
    }
  }
#pragma unroll
  for (int off = 8; off >= 1; off >>= 1)
#pragma unroll
    for (int j = 0; j < 4; ++j) {
      s1[j] += __shfl_down(s1[j], off, 64);
      s2[j] += __shfl_down(s2[j], off, 64);
    }
  if (tr == 0) {
    float* sb = statp + (size_t)(blockIdx.x & 7) * 256;
#pragma unroll
    for (int j = 0; j < 4; ++j) {
      atomicAdd(sb + c0 + j, s1[j]);
      atomicAdd(sb + 128 + c0 + j, s2[j]);
    }
  }
}

// ------- conv pass 1: gathered X[E,192] @ [Wm|Wg][192,128]; store tm (fp32) only; stats for 128 cols -------
__global__ __launch_bounds__(256)
void conv_gemm_stats(const float* __restrict__ hn, const float* __restrict__ he,
                     const int* __restrict__ src, const int* __restrict__ dst,
                     const float* __restrict__ Wm, const float* __restrict__ Wg,
                     const float* __restrict__ bm, const float* __restrict__ bg,
                     float* __restrict__ tm, float* __restrict__ statp)
{
  __shared__ float Xs[32][68];
  __shared__ float Ws[32][132];
  const int t = threadIdx.x;
  const int e0 = blockIdx.x * 64;
  const int tr = t & 15, tc = t >> 4;
  const int r0 = tr * 4, c0 = tc * 8;
  float acc[4][8] = {};
  const int lr = t >> 2;
  const int lk = (t & 3) * 8;
  const int wkb = t >> 5;
  const int wc = (t & 31) * 4;
  for (int kt = 0; kt < 6; ++kt) {
    {
      const int e = e0 + lr;
      const float* base;
      int col;
      if (kt < 2)      { base = hn + (size_t)src[e] * Fd; col = kt * 32; }
      else if (kt < 4) { base = hn + (size_t)dst[e] * Fd; col = (kt - 2) * 32; }
      else             { base = he + (size_t)e * Fd;      col = (kt - 4) * 32; }
#pragma unroll
      for (int u = 0; u < 2; ++u) {
        const int kk = lk + u * 4;
        const float4 v = *(const float4*)(base + col + kk);
        Xs[kk + 0][lr] = v.x; Xs[kk + 1][lr] = v.y;
        Xs[kk + 2][lr] = v.z; Xs[kk + 3][lr] = v.w;
      }
    }
#pragma unroll
    for (int p = 0; p < 4; ++p) {
      const int kw = p * 8 + wkb;
      const int kg = kt * 32 + kw;
      const float* wsrc = (wc < 64) ? (Wm + (size_t)kg * Fd + wc)
                                    : (Wg + (size_t)kg * Fd + (wc - 64));
      *(float4*)&Ws[kw][wc] = *(const float4*)wsrc;
    }
    __syncthreads();
#pragma unroll
    for (int k = 0; k < 32; ++k) {
      const float4 xv = *(const float4*)&Xs[k][r0];
      const float4 wva = *(const float4*)&Ws[k][c0];
      const float4 wvb = *(const float4*)&Ws[k][c0 + 4];
      const float xa[4] = {xv.x, xv.y, xv.z, xv.w};
      const float wa[8] = {wva.x, wva.y, wva.z, wva.w, wvb.x, wvb.y, wvb.z, wvb.w};
#pragma unroll
      for (int i = 0; i < 4; ++i)
#pragma unroll
        for (int j = 0; j < 8; ++j)
          acc[i][j] = fmaf(xa[i], wa[j], acc[i][j]);
    }
    __syncthreads();
  }
  float bv[8];
#pragma unroll
  for (int j = 0; j < 8; ++j) bv[j] = (c0 < 64) ? bm[c0 + j] : bg[c0 - 64 + j];
  float s1[8] = {}, s2[8] = {};
#pragma unroll
  for (int i = 0; i < 4; ++i) {
    const size_t e = (size_t)(e0 + r0 + i);
    float4 ya, yb;
    float* yap = (float*)&ya;
    float* ybp = (float*)&yb;
#pragma unroll
    for (int j = 0; j < 8; ++j) {
      const float y = acc[i][j] + bv[j];
      s1[j] += y; s2[j] += y * y;
      if (j < 4) yap[j] = y; else ybp[j - 4] = y;
    }
    if (c0 < 64) {   // store only the tm half (tg recomputed in pass 2)
      *(float4*)(tm + e * Fd + c0) = ya;
      *(float4*)(tm + e * Fd + c0 + 4) = yb;
    }
  }
#pragma unroll
  for (int off = 8; off >= 1; off >>= 1)
#pragma unroll
    for (int j = 0; j < 8; ++j) {
      s1[j] += __shfl_down(s1[j], off, 64);
      s2[j] += __shfl_down(s2[j], off, 64);
    }
  if (tr == 0) {
    float* sb = statp + (size_t)(blockIdx.x & 7) * 256;
#pragma unroll
    for (int j = 0; j < 8; ++j) {
      atomicAdd(sb + c0 + j, s1[j]);
      atomicAdd(sb + 128 + c0 + j, s2[j]);
    }
  }
}

// ------- conv pass 2: recompute tg = X @ Wg (same fma order), read tm, apply BNs+acts, scatter to agg -------
__global__ __launch_bounds__(256)
void conv_apply_gemm(const float* __restrict__ hn, const float* __restrict__ he,
                     const int* __restrict__ src, const int* __restrict__ dst,
                     const float* __restrict__ Wg, const float* __restrict__ bg,
                     const float* __restrict__ tm, const float* __restrict__ aff,
                     float* __restrict__ agg)
{
  __shared__ float Xs[32][68];
  __shared__ float Wgs[32][68];
  const int t = threadIdx.x;
  const int e0 = blockIdx.x * 64;
  const int tr = t & 15, tc = t >> 4;
  const int r0 = tr * 4, c0 = tc * 4;
  float acc[4][4] = {};
  const int lr = t >> 2;
  const int lk = (t & 3) * 8;
  const int wk = t >> 3;        // 0..31
  const int wc = (t & 7) * 8;   // 0..56
  for (int kt = 0; kt < 6; ++kt) {
    {
      const int e = e0 + lr;
      const float* base;
      int col;
      if (kt < 2)      { base = hn + (size_t)src[e] * Fd; col = kt * 32; }
      else if (kt < 4) { base = hn + (size_t)dst[e] * Fd; col = (kt - 2) * 32; }
      else             { base = he + (size_t)e * Fd;      col = (kt - 4) * 32; }
#pragma unroll
      for (int u = 0; u < 2; ++u) {
        const int kk = lk + u * 4;
        const float4 v = *(const float4*)(base + col + kk);
        Xs[kk + 0][lr] = v.x; Xs[kk + 1][lr] = v.y;
        Xs[kk + 2][lr] = v.z; Xs[kk + 3][lr] = v.w;
      }
    }
#pragma unroll
    for (int u = 0; u < 2; ++u) {
      const int cc = wc + u * 4;
      *(float4*)&Wgs[wk][cc] = *(const float4*)(Wg + (size_t)(kt * 32 + wk) * Fd + cc);
    }
    __syncthreads();
#pragma unroll
    for (int k = 0; k < 32; ++k) {
      const float4 xv = *(const float4*)&Xs[k][r0];
      const float4 wv = *(const float4*)&Wgs[k][c0];
      const float xa[4] = {xv.x, xv.y, xv.z, xv.w};
      const float wa[4] = {wv.x, wv.y, wv.z, wv.w};
#pragma unroll
      for (int i = 0; i < 4; ++i)
#pragma unroll
        for (int j = 0; j < 4; ++j)
          acc[i][j] = fmaf(xa[i], wa[j], acc[i][j]);
    }
    __syncthreads();
  }
  // per-column constants: aff layout — scale_m[c]=aff[c], scale_g[c]=aff[64+c],
  // shift_m[c]=aff[128+c], shift_g[c]=aff[192+c]
  float ams[4], amb[4], ags[4], agb[4], bgv[4];
#pragma unroll
  for (int j = 0; j < 4; ++j) {
    const int c = c0 + j;
    ams[j] = aff[c];      amb[j] = aff[128 + c];
    ags[j] = aff[64 + c]; agb[j] = aff[192 + c];
    bgv[j] = bg[c];
  }
#pragma unroll
  for (int i = 0; i < 4; ++i) {
    const int e = e0 + r0 + i;
    const int d = dst[e];
    const float4 t4 = *(const float4*)(tm + (size_t)e * Fd + c0);
    const float* tp = (const float*)&t4;
    float* ab = agg + (size_t)d * Fd + c0;
#pragma unroll
    for (int j = 0; j < 4; ++j) {
      const float m  = d_sigmoid(ams[j] * tp[j] + amb[j]);
      const float gt = d_softplus(ags[j] * (acc[i][j] + bgv[j]) + agb[j]);
      atomicAdd(ab + j, m * gt);
    }
  }
}

// ---------------- fold stats -> per-column affine (scale at aff[c], shift at aff[128+c]) ----------------
__global__ void finalize_affine(const float* __restrict__ statp, float M,
                                const float* __restrict__ g0, const float* __restrict__ be0,
                                const float* __restrict__ g1, const float* __restrict__ be1,
                                float* __restrict__ aff, int C)
{
  const int t = threadIdx.x;
  if (t >= C) return;
  float s = 0.f, ss = 0.f;
#pragma unroll
  for (int q = 0; q < 8; ++q) { s += statp[q * 256 + t]; ss += statp[q * 256 + 128 + t]; }
  const float mean = s / M;
  const float var = ss / M - mean * mean;
  const float g  = (t < 64) ? g0[t] : g1[t - 64];
  const float be = (t < 64) ? be0[t] : be1[t - 64];
  const float a = g * rsqrtf(var + EPSV);
  aff[t] = a;
  aff[128 + t] = be - mean * a;
}

// ---------------- apply BN affine + SiLU (embeddings) ----------------
__global__ __launch_bounds__(256)
void apply_embed(const float* __restrict__ Y, const float* __restrict__ aff,
                 float* __restrict__ H, int total4)
{
  for (int i = blockIdx.x * blockDim.x + threadIdx.x; i < total4; i += gridDim.x * blockDim.x) {
    const int base = i * 4;
    const int c = base & 63;
    const float4 y = *(const float4*)(Y + base);
    float4 h;
    const float* yp = (const float*)&y;
    float* hp = (float*)&h;
#pragma unroll
    for (int j = 0; j < 4; ++j) {
      const float v = aff[c + j] * yp[j] + aff[128 + c + j];
      hp[j] = d_silu(v);
    }
    *(float4*)(H + base) = h;
  }
}

// ---------------- column stats of a [M,64] fp32 matrix ----------------
__global__ __launch_bounds__(256)
void col_stats(const float* __restrict__ Y, int M, float* __restrict__ statp)
{
  __shared__ float r1[4][64], r2[4][64];
  const int t = threadIdx.x;
  const int c = t & 63, rg = t >> 6;
  float s1 = 0.f, s2 = 0.f;
  const int rb = blockIdx.x * 64;
  for (int rr = rg; rr < 64; rr += 4) {
    const int r = rb + rr;
    if (r < M) { const float v = Y[(size_t)r * 64 + c]; s1 += v; s2 += v * v; }
  }
  r1[rg][c] = s1; r2[rg][c] = s2;
  __syncthreads();
  if (rg == 0) {
    s1 = r1[0][c] + r1[1][c] + r1[2][c] + r1[3][c];
    s2 = r2[0][c] + r2[1][c] + r2[2][c] + r2[3][c];
    float* sb = statp + (size_t)(blockIdx.x & 7) * 256;
    atomicAdd(sb + c, s1);
    atomicAdd(sb + 128 + c, s2);
  }
}

// ---------------- node update: h_n = sigmoid(bn(agg) + h_n) ----------------
__global__ __launch_bounds__(256)
void node_update(const float* __restrict__ agg, const float* __restrict__ aff,
                 float* __restrict__ hn, int total4)
{
  for (int i = blockIdx.x * blockDim.x + threadIdx.x; i < total4; i += gridDim.x * blockDim.x) {
    const int base = i * 4;
    const int c = base & 63;
    const float4 a4 = *(const float4*)(agg + base);
    float4 h4 = *(float4*)(hn + base);
    const float* ap = (const float*)&a4;
    float* hp = (float*)&h4;
#pragma unroll
    for (int j = 0; j < 4; ++j) {
      const float v = aff[c + j] * ap[j] + aff[128 + c + j] + hp[j];
      hp[j] = d_sigmoid(v);
    }
    *(float4*)(hn + base) = h4;
  }
}

// ---------------- pooling scatter ----------------
__global__ __launch_bounds__(256)
void pool_scatter(const float* __restrict__ hn, const int* __restrict__ n2g,
                  float* __restrict__ psum, float* __restrict__ pcnt)
{
  const int total = Nn * 64;
  for (int v = blockIdx.x * blockDim.x + threadIdx.x; v < total; v += gridDim.x * blockDim.x) {
    const int i = v >> 6, c = v & 63;
    const int g = n2g[i];
    atomicAdd(psum + (size_t)g * 64 + c, hn[v]);
    if (c == 0) atomicAdd(pcnt + g, 1.f);
  }
}

// ---------------- FC head: pooled -> Linear+BN+SiLU -> Linear, fp32 out ----------------
__global__ __launch_bounds__(256)
void fc_head(const float* __restrict__ psum, const float* __restrict__ pcnt,
             const float* __restrict__ Wfc, const float* __restrict__ bfc,
             const float* __restrict__ gfc, const float* __restrict__ befc,
             const float* __restrict__ Wout, const float* __restrict__ bout,
             float* __restrict__ out)
{
  __shared__ float P[128][64];
  __shared__ float Yl[128][10];
  __shared__ float af[2][10];
  const int t = threadIdx.x;
  for (int i = t; i < 128 * 64; i += 256) {
    const int r = i >> 6;
    P[r][i & 63] = psum[i] / fmaxf(pcnt[r], 1.f);
  }
  __syncthreads();
  for (int o = t; o < 128 * 10; o += 256) {
    const int r = o / 10, c = o % 10;
    float s = bfc[c];
    for (int k = 0; k < 64; ++k) s = fmaf(P[r][k], Wfc[k * 10 + c], s);
    Yl[r][c] = s;
  }
  __syncthreads();
  if (t < 10) {
    float s1 = 0.f, s2 = 0.f;
    for (int r = 0; r < 128; ++r) { const float v = Yl[r][t]; s1 += v; s2 += v * v; }
    const float mean = s1 / 128.f;
    const float var = s2 / 128.f - mean * mean;
    const float a = gfc[t] * rsqrtf(var + EPSV);
    af[0][t] = a; af[1][t] = befc[t] - mean * a;
  }
  __syncthreads();
  if (t < 128) {
    float s = bout[0];
    for (int c = 0; c < 10; ++c) {
      float h = af[0][c] * Yl[t][c] + af[1][c];
      h = d_silu(h);
      s = fmaf(h, Wout[c], s);
    }
    out[t] = s;   // fp32 — the reference's output dtype
  }
}

extern "C" void kernel_launch(void* const* d_in, const int* in_sizes, int n_in,
                              void* d_out, int out_size, void* d_ws, size_t ws_size,
                              hipStream_t stream)
{
  const float* node_feats = (const float*)d_in[0];
  const float* edge_feats = (const float*)d_in[1];
  const int*   src        = (const int*)d_in[2];
  const int*   dst        = (const int*)d_in[3];
  const int*   n2g        = (const int*)d_in[4];
  const float* W_ne = (const float*)d_in[5];
  const float* b_ne = (const float*)d_in[6];
  const float* g_ne = (const float*)d_in[7];
  const float* be_ne = (const float*)d_in[8];
  const float* W_ee = (const float*)d_in[9];
  const float* b_ee = (const float*)d_in[10];
  const float* g_ee = (const float*)d_in[11];
  const float* be_ee = (const float*)d_in[12];
  const float* Wm  = (const float*)d_in[13];
  const float* bm  = (const float*)d_in[14];
  const float* gm  = (const float*)d_in[15];
  const float* bem = (const float*)d_in[16];
  const float* Wg  = (const float*)d_in[17];
  const float* bg  = (const float*)d_in[18];
  const float* gg  = (const float*)d_in[19];
  const float* beg = (const float*)d_in[20];
  const float* gn  = (const float*)d_in[21];
  const float* ben = (const float*)d_in[22];
  const float* W_fc = (const float*)d_in[23];
  const float* b_fc = (const float*)d_in[24];
  const float* g_fc = (const float*)d_in[25];
  const float* be_fc = (const float*)d_in[26];
  const float* W_out = (const float*)d_in[27];
  const float* b_out = (const float*)d_in[28];

  // workspace layout — ~217.6 MB total (fits the proven round-0 budget)
  char* ws = (char*)d_ws;
  size_t off = 0;
  float* h_n = (float*)(ws + off); off += (size_t)Nn * 64 * 4;     //   6.4 MB
  float* h_e = (float*)(ws + off); off += (size_t)Ee * 64 * 4;     // 102.4 MB
  float* tm  = (float*)(ws + off); off += (size_t)Ee * 64 * 4;     // 102.4 MB (fp32, pass-1 output)
  float* agg   = (float*)(ws + off); off += (size_t)Nn * 64 * 4;   //   6.4 MB
  float* statp = (float*)(ws + off); off += 8 * 256 * 4;
  float* aff   = (float*)(ws + off); off += 256 * 4;
  float* psum  = (float*)(ws + off); off += (size_t)Gg * 64 * 4;
  float* pcnt  = (float*)(ws + off); off += Gg * 4;
  float* tmpe  = tm;   // fp32 [E,64] overlay (pre-BN edge embed, before conv loop)

  const int STATB = 8 * 256 * 4;

  // node embedding
  hipMemsetAsync(statp, 0, STATB, stream);
  embed_gemm<NF><<<(Nn + 63) / 64, 256, 0, stream>>>(node_feats, W_ne, b_ne, agg, statp, Nn);
  finalize_affine<<<1, 128, 0, stream>>>(statp, (float)Nn, g_ne, be_ne, g_ne, be_ne, aff, 64);
  apply_embed<<<1024, 256, 0, stream>>>(agg, aff, h_n, Nn * 16);

  // edge embedding
  hipMemsetAsync(statp, 0, STATB, stream);
  embed_gemm<EF><<<Ee / 64, 256, 0, stream>>>(edge_feats, W_ee, b_ee, tmpe, statp, Ee);
  finalize_affine<<<1, 128, 0, stream>>>(statp, (float)Ee, g_ee, be_ee, g_ee, be_ee, aff, 64);
  apply_embed<<<2048, 256, 0, stream>>>(tmpe, aff, h_e, Ee * 16);

  for (int l = 0; l < NC; ++l) {
    const float* Wm_l = Wm + (size_t)l * K3 * Fd;
    const float* Wg_l = Wg + (size_t)l * K3 * Fd;
    hipMemsetAsync(statp, 0, STATB, stream);
    conv_gemm_stats<<<Ee / 64, 256, 0, stream>>>(h_n, h_e, src, dst, Wm_l, Wg_l,
                                                 bm + l * Fd, bg + l * Fd, tm, statp);
    finalize_affine<<<1, 128, 0, stream>>>(statp, (float)Ee, gm + l * Fd, bem + l * Fd,
                                           gg + l * Fd, beg + l * Fd, aff, 128);
    hipMemsetAsync(agg, 0, (size_t)Nn * 64 * 4, stream);
    conv_apply_gemm<<<Ee / 64, 256, 0, stream>>>(h_n, h_e, src, dst, Wg_l,
                                                 bg + l * Fd, tm, aff, agg);
    hipMemsetAsync(statp, 0, STATB, stream);
    col_stats<<<(Nn + 63) / 64, 256, 0, stream>>>(agg, Nn, statp);
    finalize_affine<<<1, 128, 0, stream>>>(statp, (float)Nn, gn + l * Fd, ben + l * Fd,
                                           gn + l * Fd, ben + l * Fd, aff, 64);
    node_update<<<1024, 256, 0, stream>>>(agg, aff, h_n, Nn * 16);
  }

  hipMemsetAsync(psum, 0, (Gg * 64 + Gg) * 4, stream);
  pool_scatter<<<2048, 256, 0, stream>>>(h_n, n2g, psum, pcnt);
  fc_head<<<1, 256, 0, stream>>>(psum, pcnt, W_fc, b_fc, g_fc, be_fc, W_out, b_out,
                                 (float*)d_out);
}

// Round 7
// 1557.925 us; speedup vs baseline: 1.5311x; 1.5311x over previous
//
#include <hip/hip_runtime.h>
#include <stdint.h>

#define EPSV 1e-5f

constexpr int Nn = 25000;
constexpr int Ee = 400000;
constexpr int Gg = 128;
constexpr int NF = 92;
constexpr int EF = 41;
constexpr int Fd = 64;
constexpr int K3 = 192;
constexpr int NC = 3;

__device__ __forceinline__ float d_sigmoid(float x) { return 1.f / (1.f + __expf(-x)); }
__device__ __forceinline__ float d_silu(float x)    { return x / (1.f + __expf(-x)); }
__device__ __forceinline__ float d_softplus(float x){ return fmaxf(x, 0.f) + __logf(1.f + __expf(-fabsf(x))); }

// ---------------- embedding GEMM: Y[M,64] = X[M,KIN] @ W[KIN,64] + b, with col stats ----------------
template<int KIN>
__global__ __launch_bounds__(256)
void embed_gemm(const float* __restrict__ X, const float* __restrict__ W,
                const float* __restrict__ bias, float* __restrict__ Y,
                float* __restrict__ statp, int M)
{
  constexpr int KC = 32;
  __shared__ float Xs[KC][68];
  __shared__ float Ws[KC][68];
  const int t = threadIdx.x;
  const int row0 = blockIdx.x * 64;
  const int tr = t & 15, tc = t >> 4;
  const int r0 = tr * 4, c0 = tc * 4;
  float acc[4][4] = {};
  constexpr int NKT = (KIN + KC - 1) / KC;
  const int lr = t >> 2;
  const int lk = (t & 3) * 8;
  const int wk = t >> 3;
  const int wc = (t & 7) * 8;
  for (int kt = 0; kt < NKT; ++kt) {
    const int k0 = kt * KC;
#pragma unroll
    for (int u = 0; u < 2; ++u) {
      const int kk = lk + u * 4;
      float v[4] = {0.f, 0.f, 0.f, 0.f};
      const int grow = row0 + lr;
      if (grow < M) {
        const float* xr = X + (size_t)grow * KIN + k0 + kk;
#pragma unroll
        for (int q = 0; q < 4; ++q)
          if (k0 + kk + q < KIN) v[q] = xr[q];
      }
      Xs[kk + 0][lr] = v[0]; Xs[kk + 1][lr] = v[1];
      Xs[kk + 2][lr] = v[2]; Xs[kk + 3][lr] = v[3];
    }
#pragma unroll
    for (int u = 0; u < 2; ++u) {
      const int cc = wc + u * 4;
      float4 wv = make_float4(0.f, 0.f, 0.f, 0.f);
      if (k0 + wk < KIN) wv = *(const float4*)(W + (size_t)(k0 + wk) * Fd + cc);
      *(float4*)&Ws[wk][cc] = wv;
    }
    __syncthreads();
#pragma unroll
    for (int k = 0; k < KC; ++k) {
      const float4 xv = *(const float4*)&Xs[k][r0];
      const float4 wv = *(const float4*)&Ws[k][c0];
      const float xa[4] = {xv.x, xv.y, xv.z, xv.w};
      const float wa[4] = {wv.x, wv.y, wv.z, wv.w};
#pragma unroll
      for (int i = 0; i < 4; ++i)
#pragma unroll
        for (int j = 0; j < 4; ++j)
          acc[i][j] = fmaf(xa[i], wa[j], acc[i][j]);
    }
    __syncthreads();
  }
  float bv[4];
#pragma unroll
  for (int j = 0; j < 4; ++j) bv[j] = bias[c0 + j];
  float s1[4] = {}, s2[4] = {};
#pragma unroll
  for (int i = 0; i < 4; ++i) {
    const int grow = row0 + r0 + i;
    if (grow < M) {
      float4 yv;
      float* yp = (float*)&yv;
#pragma unroll
      for (int j = 0; j < 4; ++j) {
        const float y = acc[i][j] + bv[j];
        yp[j] = y; s1[j] += y; s2[j] += y * y;
      }
      *(float4*)(Y + (size_t)grow * Fd + c0) = yv;
    }
  }
#pragma unroll
  for (int off = 8; off >= 1; off >>= 1)
#pragma unroll
    for (int j = 0; j < 4; ++j) {
      s1[j] += __shfl_down(s1[j], off, 64);
      s2[j] += __shfl_down(s2[j], off, 64);
    }
  if (tr == 0) {
    float* sb = statp + (size_t)(blockIdx.x & 7) * 256;
#pragma unroll
    for (int j = 0; j < 4; ++j) {
      atomicAdd(sb + c0 + j, s1[j]);
      atomicAdd(sb + 128 + c0 + j, s2[j]);
    }
  }
}

// ---------------- CSR build (dst-sorted edge list; dst is layer-invariant) ----------------
__global__ __launch_bounds__(256)
void hist_dst(const int* __restrict__ dst, int* __restrict__ cnt)
{
  for (int e = blockIdx.x * blockDim.x + threadIdx.x; e < Ee; e += gridDim.x * blockDim.x)
    atomicAdd(&cnt[dst[e]], 1);
}

__global__ __launch_bounds__(1024)
void scan_csr(const int* __restrict__ cnt, int* __restrict__ rp, int* __restrict__ wp)
{
  __shared__ int part[1024];
  const int t = threadIdx.x;
  constexpr int CH = 25;  // 1024*25 = 25600 >= Nn
  int s = 0;
  for (int i = 0; i < CH; ++i) {
    const int idx = t * CH + i;
    if (idx < Nn) s += cnt[idx];
  }
  part[t] = s;
  __syncthreads();
  for (int off = 1; off < 1024; off <<= 1) {
    const int v = (t >= off) ? part[t - off] : 0;
    __syncthreads();
    part[t] += v;
    __syncthreads();
  }
  int excl = (t == 0) ? 0 : part[t - 1];
  for (int i = 0; i < CH; ++i) {
    const int idx = t * CH + i;
    if (idx < Nn) { rp[idx] = excl; wp[idx] = excl; excl += cnt[idx]; }
  }
  if (t == 1023) rp[Nn] = excl;
}

__global__ __launch_bounds__(256)
void scatter_csr(const int* __restrict__ dst, int* __restrict__ wp, int* __restrict__ ord)
{
  for (int e = blockIdx.x * blockDim.x + threadIdx.x; e < Ee; e += gridDim.x * blockDim.x) {
    const int p = atomicAdd(&wp[dst[e]], 1);
    ord[p] = e;
  }
}

// ---------------- node projection: P[n][c] = sum_k hn[n][k] * Wcat[wrow0+k][c], c in [0,128) ----------------
__global__ __launch_bounds__(256)
void node_proj(const float* __restrict__ hn, const float* __restrict__ Wm,
               const float* __restrict__ Wg, float* __restrict__ P, int wrow0)
{
  __shared__ float Xs[32][68];
  __shared__ float Ws[32][132];
  const int t = threadIdx.x;
  const int row0 = blockIdx.x * 64;
  const int tr = t & 15, tc = t >> 4;
  const int r0 = tr * 4, c0 = tc * 8;
  float acc[4][8] = {};
  const int lr = t >> 2;
  const int lk = (t & 3) * 8;
  const int wkb = t >> 5;
  const int wc = (t & 31) * 4;
  for (int kt = 0; kt < 2; ++kt) {
    {
      const int grow = row0 + lr;
#pragma unroll
      for (int u = 0; u < 2; ++u) {
        const int kk = lk + u * 4;
        float4 v = make_float4(0.f, 0.f, 0.f, 0.f);
        if (grow < Nn) v = *(const float4*)(hn + (size_t)grow * Fd + kt * 32 + kk);
        Xs[kk + 0][lr] = v.x; Xs[kk + 1][lr] = v.y;
        Xs[kk + 2][lr] = v.z; Xs[kk + 3][lr] = v.w;
      }
    }
#pragma unroll
    for (int p = 0; p < 4; ++p) {
      const int kw = p * 8 + wkb;
      const int kg = wrow0 + kt * 32 + kw;
      const float* wsrc = (wc < 64) ? (Wm + (size_t)kg * Fd + wc)
                                    : (Wg + (size_t)kg * Fd + (wc - 64));
      *(float4*)&Ws[kw][wc] = *(const float4*)wsrc;
    }
    __syncthreads();
#pragma unroll
    for (int k = 0; k < 32; ++k) {
      const float4 xv = *(const float4*)&Xs[k][r0];
      const float4 wva = *(const float4*)&Ws[k][c0];
      const float4 wvb = *(const float4*)&Ws[k][c0 + 4];
      const float xa[4] = {xv.x, xv.y, xv.z, xv.w};
      const float wa[8] = {wva.x, wva.y, wva.z, wva.w, wvb.x, wvb.y, wvb.z, wvb.w};
#pragma unroll
      for (int i = 0; i < 4; ++i)
#pragma unroll
        for (int j = 0; j < 8; ++j)
          acc[i][j] = fmaf(xa[i], wa[j], acc[i][j]);
    }
    __syncthreads();
  }
#pragma unroll
  for (int i = 0; i < 4; ++i) {
    const int n = row0 + r0 + i;
    if (n < Nn) {
      float4 a, b;
      a.x = acc[i][0]; a.y = acc[i][1]; a.z = acc[i][2]; a.w = acc[i][3];
      b.x = acc[i][4]; b.y = acc[i][5]; b.z = acc[i][6]; b.w = acc[i][7];
      *(float4*)(P + (size_t)n * 128 + c0) = a;
      *(float4*)(P + (size_t)n * 128 + c0 + 4) = b;
    }
  }
}

// ------- conv pass 1: T[e,0:128] = he[e] @ Wedge(K=64) + bias + Psrc[src[e]] + Pdst[dst[e]]
//         store tm half (cols 0..63), col stats for all 128 -------
__global__ __launch_bounds__(256)
void conv_pass1(const float* __restrict__ he, const int* __restrict__ src,
                const int* __restrict__ dst,
                const float* __restrict__ Wm, const float* __restrict__ Wg,
                const float* __restrict__ bm, const float* __restrict__ bg,
                const float* __restrict__ Psrc, const float* __restrict__ Pdst,
                float* __restrict__ tm, float* __restrict__ statp)
{
  __shared__ float Xs[32][68];
  __shared__ float Ws[32][132];
  const int t = threadIdx.x;
  const int e0 = blockIdx.x * 64;
  const int tr = t & 15, tc = t >> 4;
  const int r0 = tr * 4, c0 = tc * 8;
  float acc[4][8] = {};
  const int lr = t >> 2;
  const int lk = (t & 3) * 8;
  const int wkb = t >> 5;
  const int wc = (t & 31) * 4;
  for (int kt = 0; kt < 2; ++kt) {
    {
      const float* base = he + (size_t)(e0 + lr) * Fd + kt * 32;
#pragma unroll
      for (int u = 0; u < 2; ++u) {
        const int kk = lk + u * 4;
        const float4 v = *(const float4*)(base + kk);
        Xs[kk + 0][lr] = v.x; Xs[kk + 1][lr] = v.y;
        Xs[kk + 2][lr] = v.z; Xs[kk + 3][lr] = v.w;
      }
    }
#pragma unroll
    for (int p = 0; p < 4; ++p) {
      const int kw = p * 8 + wkb;
      const int kg = 128 + kt * 32 + kw;   // edge rows of W
      const float* wsrc = (wc < 64) ? (Wm + (size_t)kg * Fd + wc)
                                    : (Wg + (size_t)kg * Fd + (wc - 64));
      *(float4*)&Ws[kw][wc] = *(const float4*)wsrc;
    }
    __syncthreads();
#pragma unroll
    for (int k = 0; k < 32; ++k) {
      const float4 xv = *(const float4*)&Xs[k][r0];
      const float4 wva = *(const float4*)&Ws[k][c0];
      const float4 wvb = *(const float4*)&Ws[k][c0 + 4];
      const float xa[4] = {xv.x, xv.y, xv.z, xv.w};
      const float wa[8] = {wva.x, wva.y, wva.z, wva.w, wvb.x, wvb.y, wvb.z, wvb.w};
#pragma unroll
      for (int i = 0; i < 4; ++i)
#pragma unroll
        for (int j = 0; j < 8; ++j)
          acc[i][j] = fmaf(xa[i], wa[j], acc[i][j]);
    }
    __syncthreads();
  }
  float bv[8];
#pragma unroll
  for (int j = 0; j < 8; ++j) bv[j] = (c0 < 64) ? bm[c0 + j] : bg[c0 - 64 + j];
  float s1[8] = {}, s2[8] = {};
#pragma unroll
  for (int i = 0; i < 4; ++i) {
    const int e = e0 + r0 + i;
    const int s = src[e], d = dst[e];
    const float* ps = Psrc + (size_t)s * 128 + c0;
    const float* pd = Pdst + (size_t)d * 128 + c0;
    float4 ya, yb;
    float* yap = (float*)&ya;
    float* ybp = (float*)&yb;
#pragma unroll
    for (int j = 0; j < 8; ++j) {
      float y = acc[i][j] + bv[j];
      y += ps[j];
      y += pd[j];
      s1[j] += y; s2[j] += y * y;
      if (j < 4) yap[j] = y; else ybp[j - 4] = y;
    }
    if (c0 < 64) {
      *(float4*)(tm + (size_t)e * Fd + c0) = ya;
      *(float4*)(tm + (size_t)e * Fd + c0 + 4) = yb;
    }
  }
#pragma unroll
  for (int off = 8; off >= 1; off >>= 1)
#pragma unroll
    for (int j = 0; j < 8; ++j) {
      s1[j] += __shfl_down(s1[j], off, 64);
      s2[j] += __shfl_down(s2[j], off, 64);
    }
  if (tr == 0) {
    float* sb = statp + (size_t)(blockIdx.x & 7) * 256;
#pragma unroll
    for (int j = 0; j < 8; ++j) {
      atomicAdd(sb + c0 + j, s1[j]);
      atomicAdd(sb + 128 + c0 + j, s2[j]);
    }
  }
}

// ------- conv pass 2: recompute tg (identical op order), read tm, msg = sig(bn_m)*sp(bn_g),
//         write msg IN PLACE over tm (coalesced, no atomics) -------
__global__ __launch_bounds__(256)
void conv_pass2(const float* __restrict__ he, const int* __restrict__ src,
                const int* __restrict__ dst, const float* __restrict__ Wg,
                const float* __restrict__ bg,
                const float* __restrict__ Psrc, const float* __restrict__ Pdst,
                const float* __restrict__ aff, float* __restrict__ tmmsg)
{
  __shared__ float Xs[32][68];
  __shared__ float Wgs[32][68];
  const int t = threadIdx.x;
  const int e0 = blockIdx.x * 64;
  const int tr = t & 15, tc = t >> 4;
  const int r0 = tr * 4, c0 = tc * 4;
  float acc[4][4] = {};
  const int lr = t >> 2;
  const int lk = (t & 3) * 8;
  const int wk = t >> 3;        // 0..31
  const int wc = (t & 7) * 8;   // 0..56
  for (int kt = 0; kt < 2; ++kt) {
    {
      const float* base = he + (size_t)(e0 + lr) * Fd + kt * 32;
#pragma unroll
      for (int u = 0; u < 2; ++u) {
        const int kk = lk + u * 4;
        const float4 v = *(const float4*)(base + kk);
        Xs[kk + 0][lr] = v.x; Xs[kk + 1][lr] = v.y;
        Xs[kk + 2][lr] = v.z; Xs[kk + 3][lr] = v.w;
      }
    }
#pragma unroll
    for (int u = 0; u < 2; ++u) {
      const int cc = wc + u * 4;
      *(float4*)&Wgs[wk][cc] = *(const float4*)(Wg + (size_t)(128 + kt * 32 + wk) * Fd + cc);
    }
    __syncthreads();
#pragma unroll
    for (int k = 0; k < 32; ++k) {
      const float4 xv = *(const float4*)&Xs[k][r0];
      const float4 wv = *(const float4*)&Wgs[k][c0];
      const float xa[4] = {xv.x, xv.y, xv.z, xv.w};
      const float wa[4] = {wv.x, wv.y, wv.z, wv.w};
#pragma unroll
      for (int i = 0; i < 4; ++i)
#pragma unroll
        for (int j = 0; j < 4; ++j)
          acc[i][j] = fmaf(xa[i], wa[j], acc[i][j]);
    }
    __syncthreads();
  }
  // aff layout: scale_m[c]=aff[c], scale_g[c]=aff[64+c], shift_m[c]=aff[128+c], shift_g[c]=aff[192+c]
  float ams[4], amb[4], ags[4], agb[4], bgv[4];
#pragma unroll
  for (int j = 0; j < 4; ++j) {
    const int c = c0 + j;
    ams[j] = aff[c];      amb[j] = aff[128 + c];
    ags[j] = aff[64 + c]; agb[j] = aff[192 + c];
    bgv[j] = bg[c];
  }
#pragma unroll
  for (int i = 0; i < 4; ++i) {
    const int e = e0 + r0 + i;
    const int s = src[e], d = dst[e];
    const float* psg = Psrc + (size_t)s * 128 + 64 + c0;
    const float* pdg = Pdst + (size_t)d * 128 + 64 + c0;
    const float4 t4 = *(const float4*)(tmmsg + (size_t)e * Fd + c0);
    const float* tp = (const float*)&t4;
    float4 o;
    float* op = (float*)&o;
#pragma unroll
    for (int j = 0; j < 4; ++j) {
      float tg = acc[i][j] + bgv[j];   // same op order as pass 1
      tg += psg[j];
      tg += pdg[j];
      const float m  = d_sigmoid(ams[j] * tp[j] + amb[j]);
      const float gt = d_softplus(ags[j] * tg + agb[j]);
      op[j] = m * gt;
    }
    *(float4*)(tmmsg + (size_t)e * Fd + c0) = o;
  }
}

// ---------------- CSR aggregation: agg[n] = sum of msg rows (one wave per node) ----------------
__global__ __launch_bounds__(256)
void agg_gather(const float* __restrict__ msg, const int* __restrict__ rp,
                const int* __restrict__ ord, float* __restrict__ agg)
{
  const int n = blockIdx.x * 4 + (threadIdx.x >> 6);
  if (n >= Nn) return;
  const int lane = threadIdx.x & 63;
  int i = rp[n];
  const int end = rp[n + 1];
  float a0 = 0.f, a1 = 0.f, a2 = 0.f, a3 = 0.f;
  for (; i + 4 <= end; i += 4) {
    const int e0 = ord[i], e1 = ord[i + 1], e2 = ord[i + 2], e3 = ord[i + 3];
    a0 += msg[(size_t)e0 * Fd + lane];
    a1 += msg[(size_t)e1 * Fd + lane];
    a2 += msg[(size_t)e2 * Fd + lane];
    a3 += msg[(size_t)e3 * Fd + lane];
  }
  for (; i < end; ++i) a0 += msg[(size_t)ord[i] * Fd + lane];
  agg[(size_t)n * Fd + lane] = (a0 + a1) + (a2 + a3);
}

// ---------------- fold stats -> per-column affine ----------------
__global__ void finalize_affine(const float* __restrict__ statp, float M,
                                const float* __restrict__ g0, const float* __restrict__ be0,
                                const float* __restrict__ g1, const float* __restrict__ be1,
                                float* __restrict__ aff, int C)
{
  const int t = threadIdx.x;
  if (t >= C) return;
  float s = 0.f, ss = 0.f;
#pragma unroll
  for (int q = 0; q < 8; ++q) { s += statp[q * 256 + t]; ss += statp[q * 256 + 128 + t]; }
  const float mean = s / M;
  const float var = ss / M - mean * mean;
  const float g  = (t < 64) ? g0[t] : g1[t - 64];
  const float be = (t < 64) ? be0[t] : be1[t - 64];
  const float a = g * rsqrtf(var + EPSV);
  aff[t] = a;
  aff[128 + t] = be - mean * a;
}

// ---------------- apply BN affine + SiLU (embeddings) ----------------
__global__ __launch_bounds__(256)
void apply_embed(const float* __restrict__ Y, const float* __restrict__ aff,
                 float* __restrict__ H, int total4)
{
  for (int i = blockIdx.x * blockDim.x + threadIdx.x; i < total4; i += gridDim.x * blockDim.x) {
    const int base = i * 4;
    const int c = base & 63;
    const float4 y = *(const float4*)(Y + base);
    float4 h;
    const float* yp = (const float*)&y;
    float* hp = (float*)&h;
#pragma unroll
    for (int j = 0; j < 4; ++j) {
      const float v = aff[c + j] * yp[j] + aff[128 + c + j];
      hp[j] = d_silu(v);
    }
    *(float4*)(H + base) = h;
  }
}

// ---------------- column stats of a [M,64] fp32 matrix ----------------
__global__ __launch_bounds__(256)
void col_stats(const float* __restrict__ Y, int M, float* __restrict__ statp)
{
  __shared__ float r1[4][64], r2[4][64];
  const int t = threadIdx.x;
  const int c = t & 63, rg = t >> 6;
  float s1 = 0.f, s2 = 0.f;
  const int rb = blockIdx.x * 64;
  for (int rr = rg; rr < 64; rr += 4) {
    const int r = rb + rr;
    if (r < M) { const float v = Y[(size_t)r * 64 + c]; s1 += v; s2 += v * v; }
  }
  r1[rg][c] = s1; r2[rg][c] = s2;
  __syncthreads();
  if (rg == 0) {
    s1 = r1[0][c] + r1[1][c] + r1[2][c] + r1[3][c];
    s2 = r2[0][c] + r2[1][c] + r2[2][c] + r2[3][c];
    float* sb = statp + (size_t)(blockIdx.x & 7) * 256;
    atomicAdd(sb + c, s1);
    atomicAdd(sb + 128 + c, s2);
  }
}

// ---------------- node update: h_n = sigmoid(bn(agg) + h_n) ----------------
__global__ __launch_bounds__(256)
void node_update(const float* __restrict__ agg, const float* __restrict__ aff,
                 float* __restrict__ hn, int total4)
{
  for (int i = blockIdx.x * blockDim.x + threadIdx.x; i < total4; i += gridDim.x * blockDim.x) {
    const int base = i * 4;
    const int c = base & 63;
    const float4 a4 = *(const float4*)(agg + base);
    float4 h4 = *(float4*)(hn + base);
    const float* ap = (const float*)&a4;
    float* hp = (float*)&h4;
#pragma unroll
    for (int j = 0; j < 4; ++j) {
      const float v = aff[c + j] * ap[j] + aff[128 + c + j] + hp[j];
      hp[j] = d_sigmoid(v);
    }
    *(float4*)(hn + base) = h4;
  }
}

// ---------------- pooling scatter ----------------
__global__ __launch_bounds__(256)
void pool_scatter(const float* __restrict__ hn, const int* __restrict__ n2g,
                  float* __restrict__ psum, float* __restrict__ pcnt)
{
  const int total = Nn * 64;
  for (int v = blockIdx.x * blockDim.x + threadIdx.x; v < total; v += gridDim.x * blockDim.x) {
    const int i = v >> 6, c = v & 63;
    const int g = n2g[i];
    atomicAdd(psum + (size_t)g * 64 + c, hn[v]);
    if (c == 0) atomicAdd(pcnt + g, 1.f);
  }
}

// ---------------- FC head: pooled -> Linear+BN+SiLU -> Linear, fp32 out ----------------
__global__ __launch_bounds__(256)
void fc_head(const float* __restrict__ psum, const float* __restrict__ pcnt,
             const float* __restrict__ Wfc, const float* __restrict__ bfc,
             const float* __restrict__ gfc, const float* __restrict__ befc,
             const float* __restrict__ Wout, const float* __restrict__ bout,
             float* __restrict__ out)
{
  __shared__ float P[128][64];
  __shared__ float Yl[128][10];
  __shared__ float af[2][10];
  const int t = threadIdx.x;
  for (int i = t; i < 128 * 64; i += 256) {
    const int r = i >> 6;
    P[r][i & 63] = psum[i] / fmaxf(pcnt[r], 1.f);
  }
  __syncthreads();
  for (int o = t; o < 128 * 10; o += 256) {
    const int r = o / 10, c = o % 10;
    float s = bfc[c];
    for (int k = 0; k < 64; ++k) s = fmaf(P[r][k], Wfc[k * 10 + c], s);
    Yl[r][c] = s;
  }
  __syncthreads();
  if (t < 10) {
    float s1 = 0.f, s2 = 0.f;
    for (int r = 0; r < 128; ++r) { const float v = Yl[r][t]; s1 += v; s2 += v * v; }
    const float mean = s1 / 128.f;
    const float var = s2 / 128.f - mean * mean;
    const float a = gfc[t] * rsqrtf(var + EPSV);
    af[0][t] = a; af[1][t] = befc[t] - mean * a;
  }
  __syncthreads();
  if (t < 128) {
    float s = bout[0];
    for (int c = 0; c < 10; ++c) {
      float h = af[0][c] * Yl[t][c] + af[1][c];
      h = d_silu(h);
      s = fmaf(h, Wout[c], s);
    }
    out[t] = s;
  }
}

extern "C" void kernel_launch(void* const* d_in, const int* in_sizes, int n_in,
                              void* d_out, int out_size, void* d_ws, size_t ws_size,
                              hipStream_t stream)
{
  const float* node_feats = (const float*)d_in[0];
  const float* edge_feats = (const float*)d_in[1];
  const int*   src        = (const int*)d_in[2];
  const int*   dst        = (const int*)d_in[3];
  const int*   n2g        = (const int*)d_in[4];
  const float* W_ne = (const float*)d_in[5];
  const float* b_ne = (const float*)d_in[6];
  const float* g_ne = (const float*)d_in[7];
  const float* be_ne = (const float*)d_in[8];
  const float* W_ee = (const float*)d_in[9];
  const float* b_ee = (const float*)d_in[10];
  const float* g_ee = (const float*)d_in[11];
  const float* be_ee = (const float*)d_in[12];
  const float* Wm  = (const float*)d_in[13];
  const float* bm  = (const float*)d_in[14];
  const float* gm  = (const float*)d_in[15];
  const float* bem = (const float*)d_in[16];
  const float* Wg  = (const float*)d_in[17];
  const float* bg  = (const float*)d_in[18];
  const float* gg  = (const float*)d_in[19];
  const float* beg = (const float*)d_in[20];
  const float* gn  = (const float*)d_in[21];
  const float* ben = (const float*)d_in[22];
  const float* W_fc = (const float*)d_in[23];
  const float* b_fc = (const float*)d_in[24];
  const float* g_fc = (const float*)d_in[25];
  const float* be_fc = (const float*)d_in[26];
  const float* W_out = (const float*)d_in[27];
  const float* b_out = (const float*)d_in[28];

  // workspace layout — ~245.2 MB total
  char* ws = (char*)d_ws;
  size_t off = 0;
  auto alloc = [&](size_t bytes) { void* p = ws + off; off += (bytes + 255) & ~(size_t)255; return p; };
  float* h_n   = (float*)alloc((size_t)Nn * 64 * 4);   //   6.4 MB
  float* h_e   = (float*)alloc((size_t)Ee * 64 * 4);   // 102.4 MB
  float* tm    = (float*)alloc((size_t)Ee * 64 * 4);   // 102.4 MB (pass-1 tm, then msg in place)
  float* agg   = (float*)alloc((size_t)Nn * 64 * 4);   //   6.4 MB
  float* Psrc  = (float*)alloc((size_t)Nn * 128 * 4);  //  12.8 MB
  float* Pdst  = (float*)alloc((size_t)Nn * 128 * 4);  //  12.8 MB
  int*   cnt   = (int*)alloc((size_t)Nn * 4);
  int*   wp    = (int*)alloc((size_t)Nn * 4);
  int*   rp    = (int*)alloc((size_t)(Nn + 1) * 4);
  int*   ord   = (int*)alloc((size_t)Ee * 4);          //   1.6 MB
  float* statp = (float*)alloc(8 * 256 * 4);
  float* aff   = (float*)alloc(256 * 4);
  float* psum  = (float*)alloc((size_t)Gg * 64 * 4);
  float* pcnt  = (float*)alloc(Gg * 4);
  float* tmpe  = tm;   // fp32 [E,64] overlay (pre-BN edge embed, before conv loop)

  const int STATB = 8 * 256 * 4;

  // CSR build (dst only — layer-invariant)
  hipMemsetAsync(cnt, 0, (size_t)Nn * 4, stream);
  hist_dst<<<512, 256, 0, stream>>>(dst, cnt);
  scan_csr<<<1, 1024, 0, stream>>>(cnt, rp, wp);
  scatter_csr<<<512, 256, 0, stream>>>(dst, wp, ord);

  // node embedding
  hipMemsetAsync(statp, 0, STATB, stream);
  embed_gemm<NF><<<(Nn + 63) / 64, 256, 0, stream>>>(node_feats, W_ne, b_ne, agg, statp, Nn);
  finalize_affine<<<1, 128, 0, stream>>>(statp, (float)Nn, g_ne, be_ne, g_ne, be_ne, aff, 64);
  apply_embed<<<1024, 256, 0, stream>>>(agg, aff, h_n, Nn * 16);

  // edge embedding
  hipMemsetAsync(statp, 0, STATB, stream);
  embed_gemm<EF><<<Ee / 64, 256, 0, stream>>>(edge_feats, W_ee, b_ee, tmpe, statp, Ee);
  finalize_affine<<<1, 128, 0, stream>>>(statp, (float)Ee, g_ee, be_ee, g_ee, be_ee, aff, 64);
  apply_embed<<<2048, 256, 0, stream>>>(tmpe, aff, h_e, Ee * 16);

  for (int l = 0; l < NC; ++l) {
    const float* Wm_l = Wm + (size_t)l * K3 * Fd;
    const float* Wg_l = Wg + (size_t)l * K3 * Fd;
    node_proj<<<(Nn + 63) / 64, 256, 0, stream>>>(h_n, Wm_l, Wg_l, Psrc, 0);
    node_proj<<<(Nn + 63) / 64, 256, 0, stream>>>(h_n, Wm_l, Wg_l, Pdst, 64);
    hipMemsetAsync(statp, 0, STATB, stream);
    conv_pass1<<<Ee / 64, 256, 0, stream>>>(h_e, src, dst, Wm_l, Wg_l,
                                            bm + l * Fd, bg + l * Fd, Psrc, Pdst, tm, statp);
    finalize_affine<<<1, 128, 0, stream>>>(statp, (float)Ee, gm + l * Fd, bem + l * Fd,
                                           gg + l * Fd, beg + l * Fd, aff, 128);
    conv_pass2<<<Ee / 64, 256, 0, stream>>>(h_e, src, dst, Wg_l, bg + l * Fd,
                                            Psrc, Pdst, aff, tm);
    agg_gather<<<(Nn + 3) / 4, 256, 0, stream>>>(tm, rp, ord, agg);
    hipMemsetAsync(statp, 0, STATB, stream);
    col_stats<<<(Nn + 63) / 64, 256, 0, stream>>>(agg, Nn, statp);
    finalize_affine<<<1, 128, 0, stream>>>(statp, (float)Nn, gn + l * Fd, ben + l * Fd,
                                           gn + l * Fd, ben + l * Fd, aff, 64);
    node_update<<<1024, 256, 0, stream>>>(agg, aff, h_n, Nn * 16);
  }

  hipMemsetAsync(psum, 0, (Gg * 64 + Gg) * 4, stream);
  pool_scatter<<<2048, 256, 0, stream>>>(h_n, n2g, psum, pcnt);
  fc_head<<<1, 256, 0, stream>>>(psum, pcnt, W_fc, b_fc, g_fc, be_fc, W_out, b_out,
                                 (float*)d_out);
}